// Round 1
// 925.858 us; speedup vs baseline: 1.0491x; 1.0491x over previous
//
#include <hip/hip_runtime.h>
#include <stdint.h>
#include <math.h>

// ---------------------------------------------------------------------------
// HebbianGroupMemory on MI355X (gfx950)
//   pair_embed [8,2048,1024] f32  -> flat [N=16384, D=1024]
//   patterns   [G=4096, D=1024] f32
//   usage      [G=4096] f32
// Outputs (concat f32): weights [16384,4096], patterns_new [4096,1024], usage_new [4096]
//
// R3 changes (vs R2 @ 971us):
//  - No-max softmax: logits bounded (<=~21.2) so exp() never overflows f32.
//    gemm1 epilogue now writes e=exp(logit) and shuffle-reduces per-row
//    partial sums -> atomicAdd rowsum[N].  softmax_kernel DELETED.
//  - scale_transpose_kernel: one streaming pass reads E, writes normalized W
//    f32 in-place + bf16 W^T + wsum column sums.  Replaces softmax (512MB)
//    + transpose (384MB) = 896MB with a single 640MB pass, and removes the
//    row-serial sync-chained softmax structure.
//  - gemm1: bijective XCD swizzle on block id (each XCD owns a contiguous
//    m-strip of Q; streams P through its own L2).
// ---------------------------------------------------------------------------

#define DECAY 0.97f
#define OMD 0.03f                 // 1 - DECAY
#define INV_TEMP (1.0f / 0.7f)
#define EPS 1e-6f
#define NORM_EPS 1e-12f

constexpr int NROWS = 16384;      // 8*2048
constexpr int DK = 1024;
constexpr int GP = 4096;

typedef unsigned short u16;
typedef __bf16 bf16x8 __attribute__((ext_vector_type(8)));   // MFMA A/B operand
typedef float f32x4 __attribute__((ext_vector_type(4)));      // MFMA C/D

// round-to-nearest-even f32 -> bf16 (as raw u16)
__device__ inline u16 f2bf(float x) {
    union { float f; uint32_t u; } c; c.f = x;
    uint32_t r = c.u + 0x7fffu + ((c.u >> 16) & 1u);
    return (u16)(r >> 16);
}

// async global->LDS, 16 bytes/lane; LDS dest = wave-uniform base + lane*16
__device__ inline void gl_lds16(const u16* g, u16* l) {
    __builtin_amdgcn_global_load_lds(
        (const __attribute__((address_space(1))) void*)g,
        (__attribute__((address_space(3))) void*)l, 16, 0, 0);
}

// ---------------------------------------------------------------------------
// Row l2-normalize: in [rows,1024] f32 -> out [rows,1024] bf16. 1 block/row.
__global__ __launch_bounds__(256) void norm_rows_kernel(
        const float* __restrict__ in, u16* __restrict__ outn) {
    __shared__ float sred[4];
    const int row = blockIdx.x;
    const int t = threadIdx.x;
    const float4 v = ((const float4*)(in + (size_t)row * DK))[t];
    float ss = v.x * v.x + v.y * v.y + v.z * v.z + v.w * v.w;
#pragma unroll
    for (int o = 32; o > 0; o >>= 1) ss += __shfl_xor(ss, o);
    if ((t & 63) == 0) sred[t >> 6] = ss;
    __syncthreads();
    const float tot = sred[0] + sred[1] + sred[2] + sred[3];
    const float rs = 1.0f / fmaxf(sqrtf(tot), NORM_EPS);
    ushort4 o4;
    o4.x = f2bf(v.x * rs); o4.y = f2bf(v.y * rs);
    o4.z = f2bf(v.z * rs); o4.w = f2bf(v.w * rs);
    ((ushort4*)(outn + (size_t)row * DK))[t] = o4;
}

// ---------------------------------------------------------------------------
// hs = log(clip(usage))/T; wsum = 0; rowsum = 0.   grid 64x256 = 16384.
__global__ __launch_bounds__(256) void prep_scalars_kernel(
        const float* __restrict__ usage, float* __restrict__ hscaled,
        float* __restrict__ wsum, float* __restrict__ rowsum) {
    const int i = blockIdx.x * 256 + threadIdx.x;
    if (i < GP) {
        hscaled[i] = logf(fmaxf(usage[i], EPS)) * INV_TEMP;
        wsum[i] = 0.0f;
    }
    rowsum[i] = 0.0f;
}

// rowsum -> 1/rowsum in place (rowsum > 0 always: sum of exps)
__global__ __launch_bounds__(256) void rowinv_kernel(float* __restrict__ rowsum) {
    const int i = blockIdx.x * 256 + threadIdx.x;
    rowsum[i] = 1.0f / rowsum[i];
}

__global__ __launch_bounds__(256) void zero_kernel(float4* __restrict__ p) {
    p[(size_t)blockIdx.x * 256 + threadIdx.x] = (float4){0.f, 0.f, 0.f, 0.f};
}

// ---------------------------------------------------------------------------
// Transpose f32 [R,C] -> bf16 [C,R].  64(r) x 256(c) tiles.
__global__ __launch_bounds__(256) void transpose_f32_bf16_kernel(
        const float* __restrict__ in, u16* __restrict__ out, int R, int C) {
    __shared__ float tile[64][260];
    const int r0 = blockIdx.x * 64;
    const int c0 = blockIdx.y * 256;
    const int t = threadIdx.x;
    const int fr = t & 63;            // float4-col (cols c0 + fr*4)
    const int rr = t >> 6;            // row base 0..3
#pragma unroll
    for (int j = 0; j < 16; ++j) {
        const int r = rr + 4 * j;
        const float4 v = *(const float4*)(in + (size_t)(r0 + r) * C + c0 + fr * 4);
        *(float4*)&tile[r][fr * 4] = v;
    }
    __syncthreads();
    __align__(16) u16 tmp[64];
#pragma unroll
    for (int r = 0; r < 64; ++r) tmp[r] = f2bf(tile[r][t]);
    u16* op = out + (size_t)(c0 + t) * R + r0;
#pragma unroll
    for (int i = 0; i < 8; ++i) ((uint4*)op)[i] = ((const uint4*)tmp)[i];
}

// ---------------------------------------------------------------------------
// Fused normalize + transpose + column-sum over E [N,G]:
//   W[n,g]   = E[n,g] * invs[n]        (f32, in-place on E)
//   wT[g,n]  = bf16(W[n,g])
//   wsum[g] += sum_n W[n,g]            (per-tile partial, 1 atomic/thread)
// 64(n) x 256(g) tiles.
__global__ __launch_bounds__(256) void scale_transpose_kernel(
        float* __restrict__ W, const float* __restrict__ invs,
        u16* __restrict__ wT, float* __restrict__ wsum) {
    __shared__ float tile[64][260];
    __shared__ float sinv[64];
    const int r0 = blockIdx.x * 64;
    const int c0 = blockIdx.y * 256;
    const int t = threadIdx.x;
    if (t < 64) sinv[t] = invs[r0 + t];
    __syncthreads();
    const int fr = t & 63;
    const int rr = t >> 6;
#pragma unroll
    for (int j = 0; j < 16; ++j) {
        const int r = rr + 4 * j;
        float4 v = *(const float4*)(W + (size_t)(r0 + r) * GP + c0 + fr * 4);
        const float s = sinv[r];
        v.x *= s; v.y *= s; v.z *= s; v.w *= s;
        *(float4*)(W + (size_t)(r0 + r) * GP + c0 + fr * 4) = v;
        *(float4*)&tile[r][fr * 4] = v;
    }
    __syncthreads();
    __align__(16) u16 tmp[64];
    float csum = 0.f;
#pragma unroll
    for (int r = 0; r < 64; ++r) {
        const float x = tile[r][t];
        csum += x;
        tmp[r] = f2bf(x);
    }
    u16* op = wT + (size_t)(c0 + t) * NROWS + r0;
#pragma unroll
    for (int i = 0; i < 8; ++i) ((uint4*)op)[i] = ((const uint4*)tmp)[i];
    atomicAdd(&wsum[c0 + t], csum);
}

// ---------------------------------------------------------------------------
// Shared 128x128 bt-GEMM mainloop: A [*,KLD], B [*,KLD] row-major bf16 (u16).
template <int KSTEPS, int KLD>
__device__ inline void gemm_bt_tile(const u16* __restrict__ A,
                                    const u16* __restrict__ B,
                                    int m0, int n0, int k0,
                                    u16* As, u16* Bs, f32x4 acc[4][4]) {
    const int t = threadIdx.x;
    const int lane = t & 63;
    const int wave = t >> 6;
    const int wm = (wave >> 1) * 64;
    const int wn = (wave & 1) * 64;
    const int fr = lane & 15;            // frag row (m for A, n for B)
    const int q8 = lane >> 4;            // quad: k-octet index component

    const int srow = 32 * wave + (lane >> 3);
    const int soct = (lane & 7) ^ ((lane >> 3) & 7);
    const size_t a_base = (size_t)(m0 + srow) * KLD + k0 + soct * 8;
    const size_t b_base = (size_t)(n0 + srow) * KLD + k0 + soct * 8;

#pragma unroll 1
    for (int kt = 0; kt < KSTEPS; kt += 64) {
        __syncthreads();   // protect previous iter's frag reads
#pragma unroll
        for (int i = 0; i < 4; ++i) {
            gl_lds16(A + a_base + (size_t)(8 * i) * KLD + kt,
                     As + (32 * wave + 8 * i) * 64);
            gl_lds16(B + b_base + (size_t)(8 * i) * KLD + kt,
                     Bs + (32 * wave + 8 * i) * 64);
        }
        __syncthreads();   // drains vmcnt (compiler emits full waitcnt)
#pragma unroll
        for (int ks8 = 0; ks8 < 8; ks8 += 4) {     // two k-steps of 32
            bf16x8 af[4], bfr[4];
#pragma unroll
            for (int f = 0; f < 4; ++f) {
                const int ra = wm + f * 16 + fr;
                af[f]  = *(const bf16x8*)(As + ra * 64 + (((ks8 + q8) ^ (ra & 7)) * 8));
                const int rb = wn + f * 16 + fr;
                bfr[f] = *(const bf16x8*)(Bs + rb * 64 + (((ks8 + q8) ^ (rb & 7)) * 8));
            }
#pragma unroll
            for (int fm = 0; fm < 4; ++fm)
#pragma unroll
                for (int fn = 0; fn < 4; ++fn)
                    acc[fm][fn] = __builtin_amdgcn_mfma_f32_16x16x32_bf16(
                        af[fm], bfr[fn], acc[fm][fn], 0, 0, 0);
        }
    }
}

// GEMM1: E[n][g] = exp((Q[n,:]·P[g,:])/T - hscaled[g]); rowsum[n] += sum_g E
__global__ __launch_bounds__(256) void gemm1_kernel(
        const u16* __restrict__ Q, const u16* __restrict__ P,
        const float* __restrict__ hs, float* __restrict__ Wout,
        float* __restrict__ rowsum) {
    __shared__ u16 As[128 * 64];
    __shared__ u16 Bs[128 * 64];
    // bijective XCD swizzle: 4096 blocks, XCD k owns a contiguous 512-block
    // chunk = 16 m-tiles x all n (Q m-strip stays hot in its L2).
    const int bid0 = blockIdx.x;
    const int bid = (bid0 & 7) * 512 + (bid0 >> 3);
    const int m0 = (bid >> 5) * 128;    // 128 m-tiles (N rows)
    const int n0 = (bid & 31) * 128;    // 32 n-tiles (G)
    f32x4 acc[4][4];
#pragma unroll
    for (int a = 0; a < 4; ++a)
#pragma unroll
        for (int b = 0; b < 4; ++b) acc[a][b] = (f32x4){0.f, 0.f, 0.f, 0.f};
    gemm_bt_tile<DK, DK>(Q, P, m0, n0, 0, As, Bs, acc);

    const int lane = threadIdx.x & 63;
    const int wave = threadIdx.x >> 6;
    const int wm = (wave >> 1) * 64, wn = (wave & 1) * 64;
    const int cq = lane & 15, rq = (lane >> 4) * 4;   // C/D: col=lane&15, row=quad*4+reg
    float hval[4];
#pragma unroll
    for (int fn = 0; fn < 4; ++fn) hval[fn] = hs[n0 + wn + fn * 16 + cq];
#pragma unroll
    for (int fm = 0; fm < 4; ++fm) {
        const int mb = m0 + wm + fm * 16 + rq;
#pragma unroll
        for (int r = 0; r < 4; ++r) {
            float rs = 0.f;
#pragma unroll
            for (int fn = 0; fn < 4; ++fn) {
                const int g = n0 + wn + fn * 16 + cq;
                const float e = __expf(acc[fm][fn][r] * INV_TEMP - hval[fn]);
                Wout[(size_t)(mb + r) * GP + g] = e;
                rs += e;
            }
            // reduce across the 16 lanes (cq) sharing this row
#pragma unroll
            for (int o = 1; o < 16; o <<= 1) rs += __shfl_xor(rs, o);
            if (cq == 0) atomicAdd(&rowsum[mb + r], rs);
        }
    }
}

// GEMM2 (split-K): Upart[g][d] += sum over K-slice of WT[g,:]·FT[d,:]
__global__ __launch_bounds__(256) void gemm2_kernel(
        const u16* __restrict__ WT, const u16* __restrict__ FT,
        float* __restrict__ Upart) {
    __shared__ u16 As[128 * 64];
    __shared__ u16 Bs[128 * 64];
    const int bid = blockIdx.x;
    const int k0 = (bid & 7) * 2048;         // k-slice = XCD key: per-XCD L2 strip
    const int n0 = ((bid >> 3) & 7) * 128;   // 8 d-tiles
    const int m0 = (bid >> 6) * 128;         // 32 g-tiles
    f32x4 acc[4][4];
#pragma unroll
    for (int a = 0; a < 4; ++a)
#pragma unroll
        for (int b = 0; b < 4; ++b) acc[a][b] = (f32x4){0.f, 0.f, 0.f, 0.f};
    gemm_bt_tile<2048, NROWS>(WT, FT, m0, n0, k0, As, Bs, acc);

    const int lane = threadIdx.x & 63;
    const int wave = threadIdx.x >> 6;
    const int wm = (wave >> 1) * 64, wn = (wave & 1) * 64;
    const int cq = lane & 15, rq = (lane >> 4) * 4;
#pragma unroll
    for (int fn = 0; fn < 4; ++fn) {
        const int d = n0 + wn + fn * 16 + cq;
#pragma unroll
        for (int fm = 0; fm < 4; ++fm) {
            const int gb = m0 + wm + fm * 16 + rq;
#pragma unroll
            for (int r = 0; r < 4; ++r)
                atomicAdd(&Upart[(size_t)(gb + r) * DK + d], acc[fm][fn][r]);
        }
    }
}

// ---------------------------------------------------------------------------
__global__ __launch_bounds__(256) void usage_kernel(
        const float* __restrict__ usage, const float* __restrict__ wsum,
        float* __restrict__ Uout, float* __restrict__ invw) {
    const int g = blockIdx.x * 256 + threadIdx.x;
    if (g < GP) {
        const float s = wsum[g];
        Uout[g] = usage[g] * DECAY + (s > 0.f ? OMD * s : 0.f);
        invw[g] = 1.0f / (s + EPS);
    }
}

// Final: blended = l2norm(DECAY*pat + OMD*Upart*invw[g]); fallback if !valid.
__global__ __launch_bounds__(256) void finalize_patterns_kernel(
        const float* __restrict__ patterns, const float* __restrict__ wsum,
        const float* __restrict__ invw, const float* __restrict__ Upart,
        float* __restrict__ Pout) {
    __shared__ float sred[4];
    const int g = blockIdx.x;
    const int t = threadIdx.x;
    const float iw = invw[g] * OMD;
    const float4 u4 = ((const float4*)(Upart + (size_t)g * DK))[t];
    const float4 p4 = ((const float4*)(patterns + (size_t)g * DK))[t];
    float4 b;
    b.x = DECAY * p4.x + iw * u4.x;
    b.y = DECAY * p4.y + iw * u4.y;
    b.z = DECAY * p4.z + iw * u4.z;
    b.w = DECAY * p4.w + iw * u4.w;
    float ss = b.x * b.x + b.y * b.y + b.z * b.z + b.w * b.w;
#pragma unroll
    for (int o = 32; o > 0; o >>= 1) ss += __shfl_xor(ss, o);
    if ((t & 63) == 0) sred[t >> 6] = ss;
    __syncthreads();
    const float tot = sred[0] + sred[1] + sred[2] + sred[3];
    const float rs = 1.0f / fmaxf(sqrtf(tot), NORM_EPS);
    float4 o4;
    if (wsum[g] > 0.f) {
        o4.x = b.x * rs; o4.y = b.y * rs; o4.z = b.z * rs; o4.w = b.w * rs;
    } else {
        o4 = p4;
    }
    ((float4*)(Pout + (size_t)g * DK))[t] = o4;
}

// ---------------------------------------------------------------------------
extern "C" void kernel_launch(void* const* d_in, const int* in_sizes, int n_in,
                              void* d_out, int out_size, void* d_ws, size_t ws_size,
                              hipStream_t stream) {
    const float* pair_embed = (const float*)d_in[0];
    const float* patterns   = (const float*)d_in[1];
    const float* usage      = (const float*)d_in[2];

    float* out_w = (float*)d_out;                       // [16384,4096]
    float* out_p = out_w + (size_t)NROWS * GP;          // [4096,1024]
    float* out_u = out_p + (size_t)GP * DK;             // [4096]

    char* ws = (char*)d_ws;
    u16* q_bf   = (u16*)(ws);                            // 32 MiB [16384,1024]; dead after gemm1
    float* Upart = (float*)(ws);                         // 16 MiB [4096,1024] (aliases q_bf)
    u16* pat_bf = (u16*)(ws + 33554432);                 //  8 MiB [4096,1024]
    u16* fT     = (u16*)(ws + 41943040);                 // 32 MiB [1024,16384]
    u16* wT     = (u16*)(ws + 75497472);                 //128 MiB [4096,16384]
    float* hs   = (float*)(ws + 209715200);              // 16 KiB
    float* wsum = (float*)(ws + 209715200 + 16384);      // 16 KiB
    float* invw = (float*)(ws + 209715200 + 32768);      // 16 KiB
    float* rsum = (float*)(ws + 209715200 + 49152);      // 64 KiB [16384] rowsum -> inv

    prep_scalars_kernel<<<64, 256, 0, stream>>>(usage, hs, wsum, rsum);
    norm_rows_kernel<<<NROWS, 256, 0, stream>>>(pair_embed, q_bf);
    norm_rows_kernel<<<GP, 256, 0, stream>>>(patterns, pat_bf);
    {   // flat^T -> bf16 [1024,16384]
        dim3 g(NROWS / 64, DK / 256);
        transpose_f32_bf16_kernel<<<g, 256, 0, stream>>>(pair_embed, fT, NROWS, DK);
    }
    gemm1_kernel<<<(NROWS / 128) * (GP / 128), 256, 0, stream>>>(q_bf, pat_bf, hs, out_w, rsum);
    rowinv_kernel<<<64, 256, 0, stream>>>(rsum);
    {   // normalize in-place + weights^T bf16 + wsum column sums
        dim3 g(NROWS / 64, GP / 256);
        scale_transpose_kernel<<<g, 256, 0, stream>>>(out_w, rsum, wT, wsum);
    }
    usage_kernel<<<16, 256, 0, stream>>>(usage, wsum, out_u, invw);
    // q_bf dead from here on; reuse its space as Upart (stream-ordered).
    zero_kernel<<<(GP * DK / 4) / 256, 256, 0, stream>>>((float4*)Upart);
    gemm2_kernel<<<8 * (GP / 128) * (DK / 128), 256, 0, stream>>>(wT, fT, Upart);
    finalize_patterns_kernel<<<GP, 256, 0, stream>>>(patterns, wsum, invw, Upart, out_p);
}

// Round 2
// 894.535 us; speedup vs baseline: 1.0859x; 1.0350x over previous
//
#include <hip/hip_runtime.h>
#include <stdint.h>
#include <math.h>

// ---------------------------------------------------------------------------
// HebbianGroupMemory on MI355X (gfx950)
//   pair_embed [8,2048,1024] f32  -> flat [N=16384, D=1024]
//   patterns   [G=4096, D=1024] f32
//   usage      [G=4096] f32
// Outputs (concat f32): weights [16384,4096], patterns_new [4096,1024], usage_new [4096]
//
// R4 changes (vs R3 @ 926us):
//  - GEMM mainloop rebuilt: 256x128 tile, 8 waves (512 thr), 3 rotating LDS
//    slots (48KB each, 144KB total, 1 block/CU) with counted vmcnt(6) and
//    RAW s_barrier (no compiler vmcnt(0) drain).  T3/T4: loads for tile t+2
//    stay in flight across the barrier; only tile t+1's are retired.
//    setprio(1) around MFMA clusters (T5).  Compute core (4x4 frags,
//    XOR-octet swizzle, 0 bank conflicts) carried over unchanged.
//  - gemm1 block order reverted to natural (m-strip) order: R3's XCD swizzle
//    blew the per-XCD L2 working set (FETCH 164->373MB). 
// ---------------------------------------------------------------------------

#define DECAY 0.97f
#define OMD 0.03f                 // 1 - DECAY
#define INV_TEMP (1.0f / 0.7f)
#define EPS 1e-6f
#define NORM_EPS 1e-12f

constexpr int NROWS = 16384;      // 8*2048
constexpr int DK = 1024;
constexpr int GP = 4096;

typedef unsigned short u16;
typedef __bf16 bf16x8 __attribute__((ext_vector_type(8)));   // MFMA A/B operand
typedef float f32x4 __attribute__((ext_vector_type(4)));      // MFMA C/D

// round-to-nearest-even f32 -> bf16 (as raw u16)
__device__ inline u16 f2bf(float x) {
    union { float f; uint32_t u; } c; c.f = x;
    uint32_t r = c.u + 0x7fffu + ((c.u >> 16) & 1u);
    return (u16)(r >> 16);
}

// async global->LDS, 16 bytes/lane; LDS dest = wave-uniform base + lane*16
__device__ inline void gl_lds16(const u16* g, u16* l) {
    __builtin_amdgcn_global_load_lds(
        (const __attribute__((address_space(1))) void*)g,
        (__attribute__((address_space(3))) void*)l, 16, 0, 0);
}

// ---------------------------------------------------------------------------
// Row l2-normalize: in [rows,1024] f32 -> out [rows,1024] bf16. 1 block/row.
__global__ __launch_bounds__(256) void norm_rows_kernel(
        const float* __restrict__ in, u16* __restrict__ outn) {
    __shared__ float sred[4];
    const int row = blockIdx.x;
    const int t = threadIdx.x;
    const float4 v = ((const float4*)(in + (size_t)row * DK))[t];
    float ss = v.x * v.x + v.y * v.y + v.z * v.z + v.w * v.w;
#pragma unroll
    for (int o = 32; o > 0; o >>= 1) ss += __shfl_xor(ss, o);
    if ((t & 63) == 0) sred[t >> 6] = ss;
    __syncthreads();
    const float tot = sred[0] + sred[1] + sred[2] + sred[3];
    const float rs = 1.0f / fmaxf(sqrtf(tot), NORM_EPS);
    ushort4 o4;
    o4.x = f2bf(v.x * rs); o4.y = f2bf(v.y * rs);
    o4.z = f2bf(v.z * rs); o4.w = f2bf(v.w * rs);
    ((ushort4*)(outn + (size_t)row * DK))[t] = o4;
}

// ---------------------------------------------------------------------------
// hs = log(clip(usage))/T; wsum = 0; rowsum = 0.   grid 64x256 = 16384.
__global__ __launch_bounds__(256) void prep_scalars_kernel(
        const float* __restrict__ usage, float* __restrict__ hscaled,
        float* __restrict__ wsum, float* __restrict__ rowsum) {
    const int i = blockIdx.x * 256 + threadIdx.x;
    if (i < GP) {
        hscaled[i] = logf(fmaxf(usage[i], EPS)) * INV_TEMP;
        wsum[i] = 0.0f;
    }
    rowsum[i] = 0.0f;
}

// rowsum -> 1/rowsum in place (rowsum > 0 always: sum of exps)
__global__ __launch_bounds__(256) void rowinv_kernel(float* __restrict__ rowsum) {
    const int i = blockIdx.x * 256 + threadIdx.x;
    rowsum[i] = 1.0f / rowsum[i];
}

__global__ __launch_bounds__(256) void zero_kernel(float4* __restrict__ p) {
    p[(size_t)blockIdx.x * 256 + threadIdx.x] = (float4){0.f, 0.f, 0.f, 0.f};
}

// ---------------------------------------------------------------------------
// Transpose f32 [R,C] -> bf16 [C,R].  64(r) x 256(c) tiles.
__global__ __launch_bounds__(256) void transpose_f32_bf16_kernel(
        const float* __restrict__ in, u16* __restrict__ out, int R, int C) {
    __shared__ float tile[64][260];
    const int r0 = blockIdx.x * 64;
    const int c0 = blockIdx.y * 256;
    const int t = threadIdx.x;
    const int fr = t & 63;            // float4-col (cols c0 + fr*4)
    const int rr = t >> 6;            // row base 0..3
#pragma unroll
    for (int j = 0; j < 16; ++j) {
        const int r = rr + 4 * j;
        const float4 v = *(const float4*)(in + (size_t)(r0 + r) * C + c0 + fr * 4);
        *(float4*)&tile[r][fr * 4] = v;
    }
    __syncthreads();
    __align__(16) u16 tmp[64];
#pragma unroll
    for (int r = 0; r < 64; ++r) tmp[r] = f2bf(tile[r][t]);
    u16* op = out + (size_t)(c0 + t) * R + r0;
#pragma unroll
    for (int i = 0; i < 8; ++i) ((uint4*)op)[i] = ((const uint4*)tmp)[i];
}

// ---------------------------------------------------------------------------
// Fused normalize + transpose + column-sum over E [N,G]:
//   W[n,g]   = E[n,g] * invs[n]        (f32, in-place on E)
//   wT[g,n]  = bf16(W[n,g])
//   wsum[g] += sum_n W[n,g]            (per-tile partial, 1 atomic/thread)
// 64(n) x 256(g) tiles.
__global__ __launch_bounds__(256) void scale_transpose_kernel(
        float* __restrict__ W, const float* __restrict__ invs,
        u16* __restrict__ wT, float* __restrict__ wsum) {
    __shared__ float tile[64][260];
    __shared__ float sinv[64];
    const int r0 = blockIdx.x * 64;
    const int c0 = blockIdx.y * 256;
    const int t = threadIdx.x;
    if (t < 64) sinv[t] = invs[r0 + t];
    __syncthreads();
    const int fr = t & 63;
    const int rr = t >> 6;
#pragma unroll
    for (int j = 0; j < 16; ++j) {
        const int r = rr + 4 * j;
        float4 v = *(const float4*)(W + (size_t)(r0 + r) * GP + c0 + fr * 4);
        const float s = sinv[r];
        v.x *= s; v.y *= s; v.z *= s; v.w *= s;
        *(float4*)(W + (size_t)(r0 + r) * GP + c0 + fr * 4) = v;
        *(float4*)&tile[r][fr * 4] = v;
    }
    __syncthreads();
    __align__(16) u16 tmp[64];
    float csum = 0.f;
#pragma unroll
    for (int r = 0; r < 64; ++r) {
        const float x = tile[r][t];
        csum += x;
        tmp[r] = f2bf(x);
    }
    u16* op = wT + (size_t)(c0 + t) * NROWS + r0;
#pragma unroll
    for (int i = 0; i < 8; ++i) ((uint4*)op)[i] = ((const uint4*)tmp)[i];
    atomicAdd(&wsum[c0 + t], csum);
}

// ---------------------------------------------------------------------------
// 256x128 bt-GEMM mainloop, 512 threads = 8 waves (4M x 2N), counted-vmcnt
// 3-slot pipeline.  A [*,KLD], B [*,KLD] row-major bf16 (u16).
// Slot layout (u16): A tile 256x64 at [0,16384), B tile 128x64 at [16384,24576).
// XOR swizzle: physical octet p of row r holds logical octet p^(r&7).
// Pipeline: iter t stages tile t+2, computes tile t, then vmcnt(6) retires
// tile t+1's 6 loads (t+2's stay in flight) before a RAW s_barrier.
template <int KSTEPS, int KLD>
__device__ inline void gemm_bt_256x128(const u16* __restrict__ A,
                                       const u16* __restrict__ B,
                                       int m0, int n0, int k0,
                                       u16* sm, f32x4 acc[4][4]) {
    constexpr int SLOT = 24576;       // u16 per slot (48 KB)
    constexpr int BOFF = 16384;       // B offset within slot (u16)
    const int t = threadIdx.x;
    const int lane = t & 63;
    const int wave = t >> 6;
    const int wm = (wave >> 1) * 64;  // 4 M-slots * 64 = 256
    const int wn = (wave & 1) * 64;   // 2 N-slots * 64 = 128
    const int fr = lane & 15;         // frag row
    const int q8 = lane >> 4;         // k-octet quad

    // staging: wave stages A rows [32w,32w+32) (4 issues), B rows [16w,16w+16) (2)
    const int arow = 32 * wave + (lane >> 3);
    const int brow = 16 * wave + (lane >> 3);
    const size_t a_base = (size_t)(m0 + arow) * KLD + k0 + (((lane & 7) ^ (arow & 7)) * 8);
    const size_t b_base = (size_t)(n0 + brow) * KLD + k0 + (((lane & 7) ^ (brow & 7)) * 8);

    auto STAGE = [&](int slot, int kt) {
        u16* sa = sm + slot * SLOT;
        u16* sb = sa + BOFF;
#pragma unroll
        for (int i = 0; i < 4; ++i)
            gl_lds16(A + a_base + (size_t)(8 * i) * KLD + kt,
                     sa + (32 * wave + 8 * i) * 64);
#pragma unroll
        for (int i = 0; i < 2; ++i)
            gl_lds16(B + b_base + (size_t)(8 * i) * KLD + kt,
                     sb + (16 * wave + 8 * i) * 64);
    };

    // prologue: stage tiles 0,1; wait tile0 (6 newest = tile1 stay in flight)
    STAGE(0, 0);
    STAGE(1, 64);
    asm volatile("s_waitcnt vmcnt(6)" ::: "memory");
    __builtin_amdgcn_sched_barrier(0);
    __builtin_amdgcn_s_barrier();
    __builtin_amdgcn_sched_barrier(0);

    int slot = 0;
#pragma unroll 1
    for (int kt = 0; kt < KSTEPS; kt += 64) {
        if (kt + 128 < KSTEPS) {
            int ss = slot + 2; if (ss >= 3) ss -= 3;
            STAGE(ss, kt + 128);
        }
        const u16* sa = sm + slot * SLOT;
        const u16* sb = sa + BOFF;
#pragma unroll
        for (int ks8 = 0; ks8 < 8; ks8 += 4) {     // two k-steps of 32
            bf16x8 af[4], bfr[4];
#pragma unroll
            for (int f = 0; f < 4; ++f) {
                const int ra = wm + f * 16 + fr;
                af[f]  = *(const bf16x8*)(sa + ra * 64 + (((ks8 + q8) ^ (ra & 7)) * 8));
                const int rb = wn + f * 16 + fr;
                bfr[f] = *(const bf16x8*)(sb + rb * 64 + (((ks8 + q8) ^ (rb & 7)) * 8));
            }
            __builtin_amdgcn_s_setprio(1);
#pragma unroll
            for (int fm = 0; fm < 4; ++fm)
#pragma unroll
                for (int fn = 0; fn < 4; ++fn)
                    acc[fm][fn] = __builtin_amdgcn_mfma_f32_16x16x32_bf16(
                        af[fm], bfr[fn], acc[fm][fn], 0, 0, 0);
            __builtin_amdgcn_s_setprio(0);
        }
        // retire tile t+1's loads; keep tile t+2's in flight (counted vmcnt)
        if (kt + 128 < KSTEPS) {
            asm volatile("s_waitcnt vmcnt(6)" ::: "memory");
        } else if (kt + 64 < KSTEPS) {
            asm volatile("s_waitcnt vmcnt(0)" ::: "memory");
        }
        __builtin_amdgcn_sched_barrier(0);
        __builtin_amdgcn_s_barrier();
        __builtin_amdgcn_sched_barrier(0);
        slot = slot + 1; if (slot >= 3) slot -= 3;
    }
}

// GEMM1: E[n][g] = exp((Q[n,:]·P[g,:])/T - hscaled[g]); rowsum[n] += sum_g E
__global__ __launch_bounds__(512) void gemm1_kernel(
        const u16* __restrict__ Q, const u16* __restrict__ P,
        const float* __restrict__ hs, float* __restrict__ Wout,
        float* __restrict__ rowsum) {
    __shared__ u16 sm[3 * 24576];     // 144 KB
    const int bid = blockIdx.x;       // natural order: consecutive blocks share m-strip
    const int m0 = (bid >> 5) * 256;  // 64 m-tiles (N rows)
    const int n0 = (bid & 31) * 128;  // 32 n-tiles (G)
    f32x4 acc[4][4];
#pragma unroll
    for (int a = 0; a < 4; ++a)
#pragma unroll
        for (int b = 0; b < 4; ++b) acc[a][b] = (f32x4){0.f, 0.f, 0.f, 0.f};
    gemm_bt_256x128<DK, DK>(Q, P, m0, n0, 0, sm, acc);

    const int lane = threadIdx.x & 63;
    const int wave = threadIdx.x >> 6;
    const int wm = (wave >> 1) * 64, wn = (wave & 1) * 64;
    const int cq = lane & 15, rq = (lane >> 4) * 4;   // C/D: col=lane&15, row=quad*4+reg
    float hval[4];
#pragma unroll
    for (int fn = 0; fn < 4; ++fn) hval[fn] = hs[n0 + wn + fn * 16 + cq];
#pragma unroll
    for (int fm = 0; fm < 4; ++fm) {
        const int mb = m0 + wm + fm * 16 + rq;
#pragma unroll
        for (int r = 0; r < 4; ++r) {
            float rs = 0.f;
#pragma unroll
            for (int fn = 0; fn < 4; ++fn) {
                const int g = n0 + wn + fn * 16 + cq;
                const float e = __expf(acc[fm][fn][r] * INV_TEMP - hval[fn]);
                Wout[(size_t)(mb + r) * GP + g] = e;
                rs += e;
            }
            // reduce across the 16 lanes (cq) sharing this row
#pragma unroll
            for (int o = 1; o < 16; o <<= 1) rs += __shfl_xor(rs, o);
            if (cq == 0) atomicAdd(&rowsum[mb + r], rs);
        }
    }
}

// GEMM2 (split-K): Upart[g][d] += sum over K-slice of WT[g,:]·FT[d,:]
__global__ __launch_bounds__(512) void gemm2_kernel(
        const u16* __restrict__ WT, const u16* __restrict__ FT,
        float* __restrict__ Upart) {
    __shared__ u16 sm[3 * 24576];     // 144 KB
    const int bid = blockIdx.x;
    const int k0 = (bid & 7) * 2048;         // k-slice = XCD key: per-XCD L2 strip
    const int n0 = ((bid >> 3) & 7) * 128;   // 8 d-tiles
    const int m0 = (bid >> 6) * 256;         // 16 g-tiles
    f32x4 acc[4][4];
#pragma unroll
    for (int a = 0; a < 4; ++a)
#pragma unroll
        for (int b = 0; b < 4; ++b) acc[a][b] = (f32x4){0.f, 0.f, 0.f, 0.f};
    gemm_bt_256x128<2048, NROWS>(WT, FT, m0, n0, k0, sm, acc);

    const int lane = threadIdx.x & 63;
    const int wave = threadIdx.x >> 6;
    const int wm = (wave >> 1) * 64, wn = (wave & 1) * 64;
    const int cq = lane & 15, rq = (lane >> 4) * 4;
#pragma unroll
    for (int fn = 0; fn < 4; ++fn) {
        const int d = n0 + wn + fn * 16 + cq;
#pragma unroll
        for (int fm = 0; fm < 4; ++fm) {
            const int gb = m0 + wm + fm * 16 + rq;
#pragma unroll
            for (int r = 0; r < 4; ++r)
                atomicAdd(&Upart[(size_t)(gb + r) * DK + d], acc[fm][fn][r]);
        }
    }
}

// ---------------------------------------------------------------------------
__global__ __launch_bounds__(256) void usage_kernel(
        const float* __restrict__ usage, const float* __restrict__ wsum,
        float* __restrict__ Uout, float* __restrict__ invw) {
    const int g = blockIdx.x * 256 + threadIdx.x;
    if (g < GP) {
        const float s = wsum[g];
        Uout[g] = usage[g] * DECAY + (s > 0.f ? OMD * s : 0.f);
        invw[g] = 1.0f / (s + EPS);
    }
}

// Final: blended = l2norm(DECAY*pat + OMD*Upart*invw[g]); fallback if !valid.
__global__ __launch_bounds__(256) void finalize_patterns_kernel(
        const float* __restrict__ patterns, const float* __restrict__ wsum,
        const float* __restrict__ invw, const float* __restrict__ Upart,
        float* __restrict__ Pout) {
    __shared__ float sred[4];
    const int g = blockIdx.x;
    const int t = threadIdx.x;
    const float iw = invw[g] * OMD;
    const float4 u4 = ((const float4*)(Upart + (size_t)g * DK))[t];
    const float4 p4 = ((const float4*)(patterns + (size_t)g * DK))[t];
    float4 b;
    b.x = DECAY * p4.x + iw * u4.x;
    b.y = DECAY * p4.y + iw * u4.y;
    b.z = DECAY * p4.z + iw * u4.z;
    b.w = DECAY * p4.w + iw * u4.w;
    float ss = b.x * b.x + b.y * b.y + b.z * b.z + b.w * b.w;
#pragma unroll
    for (int o = 32; o > 0; o >>= 1) ss += __shfl_xor(ss, o);
    if ((t & 63) == 0) sred[t >> 6] = ss;
    __syncthreads();
    const float tot = sred[0] + sred[1] + sred[2] + sred[3];
    const float rs = 1.0f / fmaxf(sqrtf(tot), NORM_EPS);
    float4 o4;
    if (wsum[g] > 0.f) {
        o4.x = b.x * rs; o4.y = b.y * rs; o4.z = b.z * rs; o4.w = b.w * rs;
    } else {
        o4 = p4;
    }
    ((float4*)(Pout + (size_t)g * DK))[t] = o4;
}

// ---------------------------------------------------------------------------
extern "C" void kernel_launch(void* const* d_in, const int* in_sizes, int n_in,
                              void* d_out, int out_size, void* d_ws, size_t ws_size,
                              hipStream_t stream) {
    const float* pair_embed = (const float*)d_in[0];
    const float* patterns   = (const float*)d_in[1];
    const float* usage      = (const float*)d_in[2];

    float* out_w = (float*)d_out;                       // [16384,4096]
    float* out_p = out_w + (size_t)NROWS * GP;          // [4096,1024]
    float* out_u = out_p + (size_t)GP * DK;             // [4096]

    char* ws = (char*)d_ws;
    u16* q_bf   = (u16*)(ws);                            // 32 MiB [16384,1024]; dead after gemm1
    float* Upart = (float*)(ws);                         // 16 MiB [4096,1024] (aliases q_bf)
    u16* pat_bf = (u16*)(ws + 33554432);                 //  8 MiB [4096,1024]
    u16* fT     = (u16*)(ws + 41943040);                 // 32 MiB [1024,16384]
    u16* wT     = (u16*)(ws + 75497472);                 //128 MiB [4096,16384]
    float* hs   = (float*)(ws + 209715200);              // 16 KiB
    float* wsum = (float*)(ws + 209715200 + 16384);      // 16 KiB
    float* invw = (float*)(ws + 209715200 + 32768);      // 16 KiB
    float* rsum = (float*)(ws + 209715200 + 49152);      // 64 KiB [16384] rowsum -> inv

    prep_scalars_kernel<<<64, 256, 0, stream>>>(usage, hs, wsum, rsum);
    norm_rows_kernel<<<NROWS, 256, 0, stream>>>(pair_embed, q_bf);
    norm_rows_kernel<<<GP, 256, 0, stream>>>(patterns, pat_bf);
    {   // flat^T -> bf16 [1024,16384]
        dim3 g(NROWS / 64, DK / 256);
        transpose_f32_bf16_kernel<<<g, 256, 0, stream>>>(pair_embed, fT, NROWS, DK);
    }
    gemm1_kernel<<<(NROWS / 256) * (GP / 128), 512, 0, stream>>>(q_bf, pat_bf, hs, out_w, rsum);
    rowinv_kernel<<<64, 256, 0, stream>>>(rsum);
    {   // normalize in-place + weights^T bf16 + wsum column sums
        dim3 g(NROWS / 64, GP / 256);
        scale_transpose_kernel<<<g, 256, 0, stream>>>(out_w, rsum, wT, wsum);
    }
    usage_kernel<<<16, 256, 0, stream>>>(usage, wsum, out_u, invw);
    // q_bf dead from here on; reuse its space as Upart (stream-ordered).
    zero_kernel<<<(GP * DK / 4) / 256, 256, 0, stream>>>((float4*)Upart);
    gemm2_kernel<<<8 * (GP / 256) * (DK / 128), 512, 0, stream>>>(wT, fT, Upart);
    finalize_patterns_kernel<<<GP, 256, 0, stream>>>(patterns, wsum, invw, Upart, out_p);
}

// Round 4
// 826.592 us; speedup vs baseline: 1.1751x; 1.0822x over previous
//
#include <hip/hip_runtime.h>
#include <stdint.h>
#include <math.h>

// ---------------------------------------------------------------------------
// HebbianGroupMemory on MI355X (gfx950)
//   pair_embed [8,2048,1024] f32  -> flat [N=16384, D=1024]
//   patterns   [G=4096, D=1024] f32
//   usage      [G=4096] f32
// Outputs (concat f32): weights [16384,4096], patterns_new [4096,1024], usage_new [4096]
//
// R6 == R5 resubmit (R5 bench failed on GPUAcquisitionTimeout; no data).
// R5 changes (vs R4 @ 894us):
//  - GEMM core rebuilt for LDS:MFMA pipe balance: 256x256 block tile, 8 waves
//    (2M x 4N), per-wave 128x64 = 8x4 frags of 16x16x32.  Per K-64 per wave:
//    24 ds_read_b128 (288 LDS-cyc) vs 64 MFMA (307 MFMA-cyc) -- balanced,
//    vs R4's 4x4 frags where LDS demand exceeded MFMA by 1.25x.
//  - 2-slot double buffer (128 KiB LDS): STAGE(t+1) issued at TOP of iter,
//    compute(t), then ONE vmcnt(0)+s_barrier at bottom.  The drain is ~free:
//    loads had the whole compute phase (~2900 cyc) to finish.
//  - gemm2 split-K 8 -> 4: K=4096/block, 256 blocks (1/CU), atomic WRITE
//    traffic halves (128->64 MB), prologue/epilogue overhead halves.
//  - XOR-octet LDS swizzle + gl_lds16 staging carried over (0 bank conflicts).
// ---------------------------------------------------------------------------

#define DECAY 0.97f
#define OMD 0.03f                 // 1 - DECAY
#define INV_TEMP (1.0f / 0.7f)
#define EPS 1e-6f
#define NORM_EPS 1e-12f

constexpr int NROWS = 16384;      // 8*2048
constexpr int DK = 1024;
constexpr int GP = 4096;

typedef unsigned short u16;
typedef __bf16 bf16x8 __attribute__((ext_vector_type(8)));   // MFMA A/B operand
typedef float f32x4 __attribute__((ext_vector_type(4)));      // MFMA C/D

// round-to-nearest-even f32 -> bf16 (as raw u16)
__device__ inline u16 f2bf(float x) {
    union { float f; uint32_t u; } c; c.f = x;
    uint32_t r = c.u + 0x7fffu + ((c.u >> 16) & 1u);
    return (u16)(r >> 16);
}

// async global->LDS, 16 bytes/lane; LDS dest = wave-uniform base + lane*16
__device__ inline void gl_lds16(const u16* g, u16* l) {
    __builtin_amdgcn_global_load_lds(
        (const __attribute__((address_space(1))) void*)g,
        (__attribute__((address_space(3))) void*)l, 16, 0, 0);
}

// ---------------------------------------------------------------------------
// Row l2-normalize: in [rows,1024] f32 -> out [rows,1024] bf16. 1 block/row.
__global__ __launch_bounds__(256) void norm_rows_kernel(
        const float* __restrict__ in, u16* __restrict__ outn) {
    __shared__ float sred[4];
    const int row = blockIdx.x;
    const int t = threadIdx.x;
    const float4 v = ((const float4*)(in + (size_t)row * DK))[t];
    float ss = v.x * v.x + v.y * v.y + v.z * v.z + v.w * v.w;
#pragma unroll
    for (int o = 32; o > 0; o >>= 1) ss += __shfl_xor(ss, o);
    if ((t & 63) == 0) sred[t >> 6] = ss;
    __syncthreads();
    const float tot = sred[0] + sred[1] + sred[2] + sred[3];
    const float rs = 1.0f / fmaxf(sqrtf(tot), NORM_EPS);
    ushort4 o4;
    o4.x = f2bf(v.x * rs); o4.y = f2bf(v.y * rs);
    o4.z = f2bf(v.z * rs); o4.w = f2bf(v.w * rs);
    ((ushort4*)(outn + (size_t)row * DK))[t] = o4;
}

// ---------------------------------------------------------------------------
// hs = log(clip(usage))/T; wsum = 0; rowsum = 0.   grid 64x256 = 16384.
__global__ __launch_bounds__(256) void prep_scalars_kernel(
        const float* __restrict__ usage, float* __restrict__ hscaled,
        float* __restrict__ wsum, float* __restrict__ rowsum) {
    const int i = blockIdx.x * 256 + threadIdx.x;
    if (i < GP) {
        hscaled[i] = logf(fmaxf(usage[i], EPS)) * INV_TEMP;
        wsum[i] = 0.0f;
    }
    rowsum[i] = 0.0f;
}

// rowsum -> 1/rowsum in place (rowsum > 0 always: sum of exps)
__global__ __launch_bounds__(256) void rowinv_kernel(float* __restrict__ rowsum) {
    const int i = blockIdx.x * 256 + threadIdx.x;
    rowsum[i] = 1.0f / rowsum[i];
}

__global__ __launch_bounds__(256) void zero_kernel(float4* __restrict__ p) {
    p[(size_t)blockIdx.x * 256 + threadIdx.x] = (float4){0.f, 0.f, 0.f, 0.f};
}

// ---------------------------------------------------------------------------
// Transpose f32 [R,C] -> bf16 [C,R].  64(r) x 256(c) tiles.
__global__ __launch_bounds__(256) void transpose_f32_bf16_kernel(
        const float* __restrict__ in, u16* __restrict__ out, int R, int C) {
    __shared__ float tile[64][260];
    const int r0 = blockIdx.x * 64;
    const int c0 = blockIdx.y * 256;
    const int t = threadIdx.x;
    const int fr = t & 63;            // float4-col (cols c0 + fr*4)
    const int rr = t >> 6;            // row base 0..3
#pragma unroll
    for (int j = 0; j < 16; ++j) {
        const int r = rr + 4 * j;
        const float4 v = *(const float4*)(in + (size_t)(r0 + r) * C + c0 + fr * 4);
        *(float4*)&tile[r][fr * 4] = v;
    }
    __syncthreads();
    __align__(16) u16 tmp[64];
#pragma unroll
    for (int r = 0; r < 64; ++r) tmp[r] = f2bf(tile[r][t]);
    u16* op = out + (size_t)(c0 + t) * R + r0;
#pragma unroll
    for (int i = 0; i < 8; ++i) ((uint4*)op)[i] = ((const uint4*)tmp)[i];
}

// ---------------------------------------------------------------------------
// Fused normalize + transpose + column-sum over E [N,G]:
//   W[n,g]   = E[n,g] * invs[n]        (f32, in-place on E)
//   wT[g,n]  = bf16(W[n,g])
//   wsum[g] += sum_n W[n,g]            (per-tile partial, 1 atomic/thread)
// 64(n) x 256(g) tiles.
__global__ __launch_bounds__(256) void scale_transpose_kernel(
        float* __restrict__ W, const float* __restrict__ invs,
        u16* __restrict__ wT, float* __restrict__ wsum) {
    __shared__ float tile[64][260];
    __shared__ float sinv[64];
    const int r0 = blockIdx.x * 64;
    const int c0 = blockIdx.y * 256;
    const int t = threadIdx.x;
    if (t < 64) sinv[t] = invs[r0 + t];
    __syncthreads();
    const int fr = t & 63;
    const int rr = t >> 6;
#pragma unroll
    for (int j = 0; j < 16; ++j) {
        const int r = rr + 4 * j;
        float4 v = *(const float4*)(W + (size_t)(r0 + r) * GP + c0 + fr * 4);
        const float s = sinv[r];
        v.x *= s; v.y *= s; v.z *= s; v.w *= s;
        *(float4*)(W + (size_t)(r0 + r) * GP + c0 + fr * 4) = v;
        *(float4*)&tile[r][fr * 4] = v;
    }
    __syncthreads();
    __align__(16) u16 tmp[64];
    float csum = 0.f;
#pragma unroll
    for (int r = 0; r < 64; ++r) {
        const float x = tile[r][t];
        csum += x;
        tmp[r] = f2bf(x);
    }
    u16* op = wT + (size_t)(c0 + t) * NROWS + r0;
#pragma unroll
    for (int i = 0; i < 8; ++i) ((uint4*)op)[i] = ((const uint4*)tmp)[i];
    atomicAdd(&wsum[c0 + t], csum);
}

// ---------------------------------------------------------------------------
// 256x256 bt-GEMM mainloop, 512 threads = 8 waves (2M x 4N), per-wave 128x64
// (8x4 frags of 16x16x32).  2-slot double buffer, one vmcnt(0)+barrier per
// K-step; stage issued at iteration top so the drain is latency-hidden.
// Slot layout (u16): A tile 256x64 at [0,16384), B tile 256x64 at [16384,32768).
// XOR swizzle: physical octet p of row r holds logical octet p^(r&7).
template <int KSTEPS, int KLD>
__device__ inline void gemm_bt_256x256(const u16* __restrict__ A,
                                       const u16* __restrict__ B,
                                       int m0, int n0, int k0,
                                       u16* sm, f32x4 acc[8][4]) {
    constexpr int SLOT = 32768;       // u16 per slot (64 KB)
    constexpr int BOFF = 16384;       // B offset within slot (u16)
    const int t = threadIdx.x;
    const int lane = t & 63;
    const int wave = t >> 6;
    const int wm = (wave >> 2) * 128; // 2 M-waves * 128 = 256
    const int wn = (wave & 3) * 64;   // 4 N-waves * 64 = 256
    const int fr = lane & 15;         // frag row
    const int q8 = lane >> 4;         // k-octet quad

    // staging: wave stages rows [32w,32w+32) of BOTH A and B (4 issues each)
    const int srow = 32 * wave + (lane >> 3);
    const int soct = (lane & 7) ^ (srow & 7);
    const size_t a_base = (size_t)(m0 + srow) * KLD + k0 + soct * 8;
    const size_t b_base = (size_t)(n0 + srow) * KLD + k0 + soct * 8;

    auto STAGE = [&](int slot, int kt) {
        u16* sa = sm + slot * SLOT;
        u16* sb = sa + BOFF;
#pragma unroll
        for (int i = 0; i < 4; ++i) {
            gl_lds16(A + a_base + (size_t)(8 * i) * KLD + kt,
                     sa + (32 * wave + 8 * i) * 64);
            gl_lds16(B + b_base + (size_t)(8 * i) * KLD + kt,
                     sb + (32 * wave + 8 * i) * 64);
        }
    };

    // prologue
    STAGE(0, 0);
    asm volatile("s_waitcnt vmcnt(0)" ::: "memory");
    __builtin_amdgcn_sched_barrier(0);
    __builtin_amdgcn_s_barrier();
    __builtin_amdgcn_sched_barrier(0);

    int slot = 0;
#pragma unroll 1
    for (int kt = 0; kt < KSTEPS; kt += 64) {
        if (kt + 64 < KSTEPS) STAGE(slot ^ 1, kt + 64);   // issue early
        const u16* sa = sm + slot * SLOT;
        const u16* sb = sa + BOFF;
#pragma unroll
        for (int ks8 = 0; ks8 < 8; ks8 += 4) {     // two k-steps of 32
            bf16x8 af[8], bfr[4];
#pragma unroll
            for (int f = 0; f < 8; ++f) {
                const int ra = wm + f * 16 + fr;
                af[f]  = *(const bf16x8*)(sa + ra * 64 + (((ks8 + q8) ^ (ra & 7)) * 8));
            }
#pragma unroll
            for (int f = 0; f < 4; ++f) {
                const int rb = wn + f * 16 + fr;
                bfr[f] = *(const bf16x8*)(sb + rb * 64 + (((ks8 + q8) ^ (rb & 7)) * 8));
            }
            __builtin_amdgcn_s_setprio(1);
#pragma unroll
            for (int fm = 0; fm < 8; ++fm)
#pragma unroll
                for (int fn = 0; fn < 4; ++fn)
                    acc[fm][fn] = __builtin_amdgcn_mfma_f32_16x16x32_bf16(
                        af[fm], bfr[fn], acc[fm][fn], 0, 0, 0);
            __builtin_amdgcn_s_setprio(0);
        }
        // staged loads for t+1 had the whole compute to land: drain is ~free
        if (kt + 64 < KSTEPS) {
            asm volatile("s_waitcnt vmcnt(0)" ::: "memory");
            __builtin_amdgcn_sched_barrier(0);
            __builtin_amdgcn_s_barrier();
            __builtin_amdgcn_sched_barrier(0);
        }
        slot ^= 1;
    }
}

// GEMM1: E[n][g] = exp((Q[n,:]·P[g,:])/T - hscaled[g]); rowsum[n] += sum_g E
__global__ __launch_bounds__(512, 2) void gemm1_kernel(
        const u16* __restrict__ Q, const u16* __restrict__ P,
        const float* __restrict__ hs, float* __restrict__ Wout,
        float* __restrict__ rowsum) {
    __shared__ u16 sm[2 * 32768];     // 128 KB
    const int bid = blockIdx.x;       // natural order: consecutive blocks share m-strip
    const int m0 = (bid >> 4) * 256;  // 64 m-tiles (N rows)
    const int n0 = (bid & 15) * 256;  // 16 n-tiles (G)
    f32x4 acc[8][4];
#pragma unroll
    for (int a = 0; a < 8; ++a)
#pragma unroll
        for (int b = 0; b < 4; ++b) acc[a][b] = (f32x4){0.f, 0.f, 0.f, 0.f};
    gemm_bt_256x256<DK, DK>(Q, P, m0, n0, 0, sm, acc);

    const int lane = threadIdx.x & 63;
    const int wave = threadIdx.x >> 6;
    const int wm = (wave >> 2) * 128, wn = (wave & 3) * 64;
    const int cq = lane & 15, rq = (lane >> 4) * 4;   // C/D: col=lane&15, row=quad*4+reg
    float hval[4];
#pragma unroll
    for (int fn = 0; fn < 4; ++fn) hval[fn] = hs[n0 + wn + fn * 16 + cq];
#pragma unroll
    for (int fm = 0; fm < 8; ++fm) {
        const int mb = m0 + wm + fm * 16 + rq;
#pragma unroll
        for (int r = 0; r < 4; ++r) {
            float rs = 0.f;
#pragma unroll
            for (int fn = 0; fn < 4; ++fn) {
                const int g = n0 + wn + fn * 16 + cq;
                const float e = __expf(acc[fm][fn][r] * INV_TEMP - hval[fn]);
                Wout[(size_t)(mb + r) * GP + g] = e;
                rs += e;
            }
            // reduce across the 16 lanes (cq) sharing this row
#pragma unroll
            for (int o = 1; o < 16; o <<= 1) rs += __shfl_xor(rs, o);
            if (cq == 0) atomicAdd(&rowsum[mb + r], rs);
        }
    }
}

// GEMM2 (split-K 4): Upart[g][d] += sum over K-slice of WT[g,:]·FT[d,:]
__global__ __launch_bounds__(512, 2) void gemm2_kernel(
        const u16* __restrict__ WT, const u16* __restrict__ FT,
        float* __restrict__ Upart) {
    __shared__ u16 sm[2 * 32768];     // 128 KB
    const int bid = blockIdx.x;
    const int k0 = (bid & 3) * 4096;         // 4 k-slices
    const int n0 = ((bid >> 2) & 3) * 256;   // 4 d-tiles
    const int m0 = (bid >> 4) * 256;         // 16 g-tiles
    f32x4 acc[8][4];
#pragma unroll
    for (int a = 0; a < 8; ++a)
#pragma unroll
        for (int b = 0; b < 4; ++b) acc[a][b] = (f32x4){0.f, 0.f, 0.f, 0.f};
    gemm_bt_256x256<4096, NROWS>(WT, FT, m0, n0, k0, sm, acc);

    const int lane = threadIdx.x & 63;
    const int wave = threadIdx.x >> 6;
    const int wm = (wave >> 2) * 128, wn = (wave & 3) * 64;
    const int cq = lane & 15, rq = (lane >> 4) * 4;
#pragma unroll
    for (int fn = 0; fn < 4; ++fn) {
        const int d = n0 + wn + fn * 16 + cq;
#pragma unroll
        for (int fm = 0; fm < 8; ++fm) {
            const int gb = m0 + wm + fm * 16 + rq;
#pragma unroll
            for (int r = 0; r < 4; ++r)
                atomicAdd(&Upart[(size_t)(gb + r) * DK + d], acc[fm][fn][r]);
        }
    }
}

// ---------------------------------------------------------------------------
__global__ __launch_bounds__(256) void usage_kernel(
        const float* __restrict__ usage, const float* __restrict__ wsum,
        float* __restrict__ Uout, float* __restrict__ invw) {
    const int g = blockIdx.x * 256 + threadIdx.x;
    if (g < GP) {
        const float s = wsum[g];
        Uout[g] = usage[g] * DECAY + (s > 0.f ? OMD * s : 0.f);
        invw[g] = 1.0f / (s + EPS);
    }
}

// Final: blended = l2norm(DECAY*pat + OMD*Upart*invw[g]); fallback if !valid.
__global__ __launch_bounds__(256) void finalize_patterns_kernel(
        const float* __restrict__ patterns, const float* __restrict__ wsum,
        const float* __restrict__ invw, const float* __restrict__ Upart,
        float* __restrict__ Pout) {
    __shared__ float sred[4];
    const int g = blockIdx.x;
    const int t = threadIdx.x;
    const float iw = invw[g] * OMD;
    const float4 u4 = ((const float4*)(Upart + (size_t)g * DK))[t];
    const float4 p4 = ((const float4*)(patterns + (size_t)g * DK))[t];
    float4 b;
    b.x = DECAY * p4.x + iw * u4.x;
    b.y = DECAY * p4.y + iw * u4.y;
    b.z = DECAY * p4.z + iw * u4.z;
    b.w = DECAY * p4.w + iw * u4.w;
    float ss = b.x * b.x + b.y * b.y + b.z * b.z + b.w * b.w;
#pragma unroll
    for (int o = 32; o > 0; o >>= 1) ss += __shfl_xor(ss, o);
    if ((t & 63) == 0) sred[t >> 6] = ss;
    __syncthreads();
    const float tot = sred[0] + sred[1] + sred[2] + sred[3];
    const float rs = 1.0f / fmaxf(sqrtf(tot), NORM_EPS);
    float4 o4;
    if (wsum[g] > 0.f) {
        o4.x = b.x * rs; o4.y = b.y * rs; o4.z = b.z * rs; o4.w = b.w * rs;
    } else {
        o4 = p4;
    }
    ((float4*)(Pout + (size_t)g * DK))[t] = o4;
}

// ---------------------------------------------------------------------------
extern "C" void kernel_launch(void* const* d_in, const int* in_sizes, int n_in,
                              void* d_out, int out_size, void* d_ws, size_t ws_size,
                              hipStream_t stream) {
    const float* pair_embed = (const float*)d_in[0];
    const float* patterns   = (const float*)d_in[1];
    const float* usage      = (const float*)d_in[2];

    float* out_w = (float*)d_out;                       // [16384,4096]
    float* out_p = out_w + (size_t)NROWS * GP;          // [4096,1024]
    float* out_u = out_p + (size_t)GP * DK;             // [4096]

    char* ws = (char*)d_ws;
    u16* q_bf   = (u16*)(ws);                            // 32 MiB [16384,1024]; dead after gemm1
    float* Upart = (float*)(ws);                         // 16 MiB [4096,1024] (aliases q_bf)
    u16* pat_bf = (u16*)(ws + 33554432);                 //  8 MiB [4096,1024]
    u16* fT     = (u16*)(ws + 41943040);                 // 32 MiB [1024,16384]
    u16* wT     = (u16*)(ws + 75497472);                 //128 MiB [4096,16384]
    float* hs   = (float*)(ws + 209715200);              // 16 KiB
    float* wsum = (float*)(ws + 209715200 + 16384);      // 16 KiB
    float* invw = (float*)(ws + 209715200 + 32768);      // 16 KiB
    float* rsum = (float*)(ws + 209715200 + 49152);      // 64 KiB [16384] rowsum -> inv

    prep_scalars_kernel<<<64, 256, 0, stream>>>(usage, hs, wsum, rsum);
    norm_rows_kernel<<<NROWS, 256, 0, stream>>>(pair_embed, q_bf);
    norm_rows_kernel<<<GP, 256, 0, stream>>>(patterns, pat_bf);
    {   // flat^T -> bf16 [1024,16384]
        dim3 g(NROWS / 64, DK / 256);
        transpose_f32_bf16_kernel<<<g, 256, 0, stream>>>(pair_embed, fT, NROWS, DK);
    }
    gemm1_kernel<<<(NROWS / 256) * (GP / 256), 512, 0, stream>>>(q_bf, pat_bf, hs, out_w, rsum);
    rowinv_kernel<<<64, 256, 0, stream>>>(rsum);
    {   // normalize in-place + weights^T bf16 + wsum column sums
        dim3 g(NROWS / 64, GP / 256);
        scale_transpose_kernel<<<g, 256, 0, stream>>>(out_w, rsum, wT, wsum);
    }
    usage_kernel<<<16, 256, 0, stream>>>(usage, wsum, out_u, invw);
    // q_bf dead from here on; reuse its space as Upart (stream-ordered).
    zero_kernel<<<(GP * DK / 4) / 256, 256, 0, stream>>>((float4*)Upart);
    gemm2_kernel<<<4 * (GP / 256) * (DK / 256), 512, 0, stream>>>(wT, fT, Upart);
    finalize_patterns_kernel<<<GP, 256, 0, stream>>>(patterns, wsum, invw, Upart, out_p);
}